// Round 1
// baseline (504.906 us; speedup 1.0000x reference)
//
#include <hip/hip_runtime.h>
#include <hip/hip_bf16.h>

// MaskMLP: x[1024,4096] -> L0 dense (4096->128*32) -> 4 block-diagonal layers
// (per-module 32->64->128->256->512) -> per-module dot with Wout -> sigmoid.
// Strategy: convert everything to bf16, run all GEMMs with 16x16x32 bf16 MFMA
// (fp32 accumulate), fuse the Wout dot into layer-4's epilogue via quad
// shuffle-reduce + fp32 atomics.

using bf16 = __hip_bfloat16;
typedef short bf16x8 __attribute__((ext_vector_type(8)));   // 8 bf16 = 4 VGPRs
typedef float f32x4 __attribute__((ext_vector_type(4)));

constexpr int B_ = 1024;   // batch
constexpr int M_ = 128;    // modules

// ---------------- fp32 -> bf16 conversion (vectorized) ----------------
__global__ void cvt_f32_bf16(const float* __restrict__ in, bf16* __restrict__ out, int n4) {
    int i = blockIdx.x * blockDim.x + threadIdx.x;
    if (i >= n4) return;
    float4 v = ((const float4*)in)[i];
    union { bf16 h[4]; short4 s; } u;
    u.h[0] = __float2bfloat16(v.x);
    u.h[1] = __float2bfloat16(v.y);
    u.h[2] = __float2bfloat16(v.z);
    u.h[3] = __float2bfloat16(v.w);
    ((short4*)out)[i] = u.s;
}

__global__ void zero_f32(float* __restrict__ p, int n) {
    int i = blockIdx.x * blockDim.x + threadIdx.x;
    if (i < n) p[i] = 0.f;
}

__global__ void final_sigmoid(const float* __restrict__ logits, const float* __restrict__ bout,
                              float* __restrict__ out, int n) {
    int i = blockIdx.x * blockDim.x + threadIdx.x;
    if (i < n) {
        float x = logits[i] + bout[i & (M_ - 1)];
        out[i] = 1.f / (1.f + __expf(-x));
    }
}

// ---------------- grouped bf16 MFMA GEMM:  C = relu(A @ W^T + bias) ----------------
// A: rows = batch, row stride lda, module offset aMod (elements)
// W: [N][K] contiguous per module, module stride wMod
// grid: (N/BN, B/BM, M).  4 waves arranged 2x2; wave tile (BM/2)x(BN/2).
// LDS k-chunk-major [BK/8][rows][8] -> sequential ds_read_b128/ds_write_b128.
// FUSE: instead of storing C, dot relu(C) rows with wout[m][col] into logits.
template<int BM, int BN, bool FUSE>
__global__ __launch_bounds__(256)
void gemm_bt_relu(const bf16* __restrict__ A, int lda, int aMod,
                  const bf16* __restrict__ W, int wMod,
                  const float* __restrict__ bias, int biasMod,
                  bf16* __restrict__ C, int ldc, int cMod,
                  int K,
                  const bf16* __restrict__ wout, int woutMod,
                  float* __restrict__ logits) {
    constexpr int BK = 32;
    constexpr int WM = BM / 2, WN = BN / 2;
    constexpr int TM = WM / 16, TN = WN / 16;

    __shared__ __align__(16) bf16 sA[BK / 8][BM][8];
    __shared__ __align__(16) bf16 sB[BK / 8][BN][8];

    const int tid = threadIdx.x;
    const int wid = tid >> 6;
    const int lane = tid & 63;
    const int wm = wid >> 1, wn = wid & 1;
    const int q = lane >> 4, ln = lane & 15;

    const int m = blockIdx.z;
    const bf16* Am = A + (size_t)m * aMod;
    const bf16* Wm = W + (size_t)m * wMod;

    const int r0 = blockIdx.y * BM;   // batch-row tile origin
    const int c0 = blockIdx.x * BN;   // out-col tile origin

    f32x4 acc[TM][TN];
#pragma unroll
    for (int i = 0; i < TM; ++i)
#pragma unroll
        for (int j = 0; j < TN; ++j)
            acc[i][j] = (f32x4){0.f, 0.f, 0.f, 0.f};

    for (int k0 = 0; k0 < K; k0 += BK) {
        // ---- stage A tile: BM rows x 32 k (4 chunks of 8 bf16 = 16B) ----
        constexpr int A_IT = BM * (BK / 8) / 256;
#pragma unroll
        for (int it = 0; it < A_IT; ++it) {
            int idx = tid + it * 256;
            int cj = idx / BM, r = idx % BM;
            *(bf16x8*)&sA[cj][r][0] =
                *(const bf16x8*)(Am + (size_t)(r0 + r) * lda + k0 + cj * 8);
        }
        // ---- stage W tile: BN rows x 32 k ----
        constexpr int B_IT = BN * (BK / 8) / 256;
#pragma unroll
        for (int it = 0; it < B_IT; ++it) {
            int idx = tid + it * 256;
            int cj = idx / BN, r = idx % BN;
            *(bf16x8*)&sB[cj][r][0] =
                *(const bf16x8*)(Wm + (size_t)(c0 + r) * K + k0 + cj * 8);
        }
        __syncthreads();

        bf16x8 aF[TM], bF[TN];
#pragma unroll
        for (int i = 0; i < TM; ++i)
            aF[i] = *(const bf16x8*)&sA[q][wm * WM + i * 16 + ln][0];
#pragma unroll
        for (int j = 0; j < TN; ++j)
            bF[j] = *(const bf16x8*)&sB[q][wn * WN + j * 16 + ln][0];
#pragma unroll
        for (int i = 0; i < TM; ++i)
#pragma unroll
            for (int j = 0; j < TN; ++j)
                acc[i][j] = __builtin_amdgcn_mfma_f32_16x16x32_bf16(aF[i], bF[j], acc[i][j], 0, 0, 0);
        __syncthreads();   // protect LDS before next stage
    }

    const float* biasm = bias + (size_t)m * biasMod;

    if (!FUSE) {
        bf16* Cm = C + (size_t)m * cMod;
#pragma unroll
        for (int j = 0; j < TN; ++j) {
            int col = c0 + wn * WN + j * 16 + ln;
            float bv = biasm[col];
#pragma unroll
            for (int i = 0; i < TM; ++i) {
#pragma unroll
                for (int r = 0; r < 4; ++r) {
                    int row = r0 + wm * WM + i * 16 + q * 4 + r;
                    float v = acc[i][j][r] + bv;
                    v = v > 0.f ? v : 0.f;
                    Cm[(size_t)row * ldc + col] = __float2bfloat16(v);
                }
            }
        }
    } else {
        // fused output layer: logits[row][m] += sum_col relu(v) * wout[m][col]
        const bf16* wom = wout + (size_t)m * woutMod;
        float wv[TN], bvv[TN];
#pragma unroll
        for (int j = 0; j < TN; ++j) {
            int col = c0 + wn * WN + j * 16 + ln;
            wv[j] = __bfloat162float(wom[col]);
            bvv[j] = biasm[col];
        }
#pragma unroll
        for (int i = 0; i < TM; ++i) {
#pragma unroll
            for (int r = 0; r < 4; ++r) {
                float p = 0.f;
#pragma unroll
                for (int j = 0; j < TN; ++j) {
                    float v = acc[i][j][r] + bvv[j];
                    v = v > 0.f ? v : 0.f;
                    p += v * wv[j];
                }
                // reduce over the 16 column-lanes of this quad (xor keeps quad bits)
                p += __shfl_xor(p, 1);
                p += __shfl_xor(p, 2);
                p += __shfl_xor(p, 4);
                p += __shfl_xor(p, 8);
                if (ln == 0) {
                    int row = r0 + wm * WM + i * 16 + q * 4 + r;
                    atomicAdd(&logits[(size_t)row * M_ + m], p);
                }
            }
        }
    }
}

// ---------------- host ----------------
extern "C" void kernel_launch(void* const* d_in, const int* in_sizes, int n_in,
                              void* d_out, int out_size, void* d_ws, size_t ws_size,
                              hipStream_t stream) {
    const float* x    = (const float*)d_in[0];
    const float* W0   = (const float*)d_in[1];
    const float* b0   = (const float*)d_in[2];
    const float* W1   = (const float*)d_in[3];
    const float* b1   = (const float*)d_in[4];
    const float* W2   = (const float*)d_in[5];
    const float* b2   = (const float*)d_in[6];
    const float* W3   = (const float*)d_in[7];
    const float* b3   = (const float*)d_in[8];
    const float* W4   = (const float*)d_in[9];
    const float* b4   = (const float*)d_in[10];
    const float* Wout = (const float*)d_in[11];
    const float* bout = (const float*)d_in[12];
    float* out = (float*)d_out;

    // workspace carve-up (all 256B-aligned), ~203 MiB total
    char* ws = (char*)d_ws;
    size_t off = 0;
    auto alloc = [&](size_t bytes) -> void* {
        off = (off + 255) & ~(size_t)255;
        void* p = ws + off;
        off += bytes;
        return p;
    };
    bf16* W0b   = (bf16*)alloc((size_t)4096 * 4096 * 2);
    bf16* W1b   = (bf16*)alloc((size_t)M_ * 64 * 32 * 2);
    bf16* W2b   = (bf16*)alloc((size_t)M_ * 128 * 64 * 2);
    bf16* W3b   = (bf16*)alloc((size_t)M_ * 256 * 128 * 2);
    bf16* W4b   = (bf16*)alloc((size_t)M_ * 512 * 256 * 2);
    bf16* Woutb = (bf16*)alloc((size_t)M_ * 512 * 2);
    bf16* xb    = (bf16*)alloc((size_t)B_ * 4096 * 2);
    bf16* h0    = (bf16*)alloc((size_t)B_ * 4096 * 2);          // [B][128][32]
    bf16* h1    = (bf16*)alloc((size_t)B_ * M_ * 64 * 2);       // [B][128][64]
    bf16* h2    = (bf16*)alloc((size_t)B_ * M_ * 128 * 2);      // [B][128][128]
    bf16* h3    = (bf16*)alloc((size_t)B_ * M_ * 256 * 2);      // [B][128][256]
    float* logits = (float*)alloc((size_t)B_ * M_ * 4);

    auto cvt = [&](const float* src, bf16* dst, size_t n) {
        int n4 = (int)(n / 4);
        cvt_f32_bf16<<<(n4 + 255) / 256, 256, 0, stream>>>(src, dst, n4);
    };
    cvt(x, xb, (size_t)B_ * 4096);
    cvt(W0, W0b, (size_t)4096 * 4096);
    cvt(W1, W1b, (size_t)M_ * 64 * 32);
    cvt(W2, W2b, (size_t)M_ * 128 * 64);
    cvt(W3, W3b, (size_t)M_ * 256 * 128);
    cvt(W4, W4b, (size_t)M_ * 512 * 256);
    cvt(Wout, Woutb, (size_t)M_ * 512);

    // L0: h0[1024,4096] = relu(xb @ W0b^T + b0)
    {
        dim3 g(4096 / 128, B_ / 128, 1);
        gemm_bt_relu<128, 128, false><<<g, 256, 0, stream>>>(
            xb, 4096, 0, W0b, 0, b0, 0, h0, 4096, 0, 4096, nullptr, 0, nullptr);
    }
    // L1: per-module 32->64
    {
        dim3 g(64 / 64, B_ / 64, M_);
        gemm_bt_relu<64, 64, false><<<g, 256, 0, stream>>>(
            h0, 4096, 32, W1b, 64 * 32, b1, 64, h1, M_ * 64, 64, 32, nullptr, 0, nullptr);
    }
    // L2: per-module 64->128
    {
        dim3 g(128 / 64, B_ / 64, M_);
        gemm_bt_relu<64, 64, false><<<g, 256, 0, stream>>>(
            h1, M_ * 64, 64, W2b, 128 * 64, b2, 128, h2, M_ * 128, 128, 64, nullptr, 0, nullptr);
    }
    // L3: per-module 128->256
    {
        dim3 g(256 / 128, B_ / 128, M_);
        gemm_bt_relu<128, 128, false><<<g, 256, 0, stream>>>(
            h2, M_ * 128, 128, W3b, 256 * 128, b3, 256, h3, M_ * 256, 256, 128, nullptr, 0, nullptr);
    }
    // zero logits, then L4 (per-module 256->512) with fused Wout dot
    zero_f32<<<(B_ * M_ + 255) / 256, 256, 0, stream>>>(logits, B_ * M_);
    {
        dim3 g(512 / 128, B_ / 128, M_);
        gemm_bt_relu<128, 128, true><<<g, 256, 0, stream>>>(
            h3, M_ * 256, 256, W4b, 512 * 256, b4, 512, nullptr, 0, 0, 256, Woutb, 512, logits);
    }
    final_sigmoid<<<(B_ * M_ + 255) / 256, 256, 0, stream>>>(logits, bout, out, B_ * M_);
}

// Round 2
// 415.956 us; speedup vs baseline: 1.2138x; 1.2138x over previous
//
#include <hip/hip_runtime.h>
#include <hip/hip_bf16.h>

// MaskMLP: x[1024,4096] -> L0 dense (4096->128*32) -> 4 block-diagonal layers
// (per-module 32->64->128->256->512) -> per-module dot with Wout -> sigmoid.
// R2: m97-style staging — global_load_lds width=16 direct-to-LDS, row-major
// LDS tiles (64B rows, coalesced 16x64B segments per wave-load), L0 tile
// 128x64 (512 blocks -> 2 blocks/CU vs 1 before), fused single cvt kernel.

using bf16 = __hip_bfloat16;
typedef short bf16x8 __attribute__((ext_vector_type(8)));   // 8 bf16 = 4 VGPRs
typedef float f32x4 __attribute__((ext_vector_type(4)));

constexpr int B_ = 1024;   // batch
constexpr int M_ = 128;    // modules

// ---------------- async global->LDS, 16B per lane ----------------
// HW semantics: LDS dest = wave-uniform base + lane*16 (m104/m108). Caller
// arranges the LDS layout so lane*16 lands exactly where lane's data belongs.
__device__ __forceinline__ void gload16_lds(const bf16* gp, bf16* lp) {
    __builtin_amdgcn_global_load_lds(
        (__attribute__((address_space(1))) void*)const_cast<bf16*>(gp),
        (__attribute__((address_space(3))) void*)lp,
        16, 0, 0);
}

// ---------------- fused fp32 -> bf16 conversion for all 7 inputs ----------------
struct CvtArgs {
    const float4* src[7];
    short4* dst[7];
};
// cumulative float4 counts: x, W0, W1, W2, W3, W4, Wout
__global__ void cvt_all(CvtArgs a) {
    constexpr int starts[8] = {0, 1048576, 5242880, 5308416, 5570560,
                               6619136, 10813440, 10829824};
    int i = blockIdx.x * blockDim.x + threadIdx.x;
    if (i >= starts[7]) return;
    int s = 0;
#pragma unroll
    for (int k = 1; k < 7; ++k) s += (i >= starts[k]) ? 1 : 0;
    int off = i - starts[s];
    float4 v = a.src[s][off];
    union { bf16 h[4]; short4 s4; } u;
    u.h[0] = __float2bfloat16(v.x);
    u.h[1] = __float2bfloat16(v.y);
    u.h[2] = __float2bfloat16(v.z);
    u.h[3] = __float2bfloat16(v.w);
    a.dst[s][off] = u.s4;
}

__global__ void zero_f32(float* __restrict__ p, int n) {
    int i = blockIdx.x * blockDim.x + threadIdx.x;
    if (i < n) p[i] = 0.f;
}

__global__ void final_sigmoid(const float* __restrict__ logits, const float* __restrict__ bout,
                              float* __restrict__ out, int n) {
    int i = blockIdx.x * blockDim.x + threadIdx.x;
    if (i < n) {
        float x = logits[i] + bout[i & (M_ - 1)];
        out[i] = 1.f / (1.f + __expf(-x));
    }
}

// ---------------- grouped bf16 MFMA GEMM:  C = relu(A @ W^T + bias) ----------------
// A: rows = batch, row stride lda, module offset aMod (elements)
// W: [N][K] contiguous per module, module stride wMod
// grid: (N/BN, B/BM, M).  4 waves arranged 2x2; wave tile (BM/2)x(BN/2).
// LDS tiles row-major [rows][BK] (64B rows). Staging: global_load_lds, each
// wave-load covers 16 rows x 32k: lane -> (row=lane/4, kchunk=lane%4), i.e.
// 16 coalesced 64B global segments -> LDS base + lane*16.
// FUSE: instead of storing C, dot relu(C) rows with wout[m][col] into logits.
template<int BM, int BN, bool FUSE>
__global__ __launch_bounds__(256)
void gemm_bt_relu(const bf16* __restrict__ A, int lda, int aMod,
                  const bf16* __restrict__ W, int wMod,
                  const float* __restrict__ bias, int biasMod,
                  bf16* __restrict__ C, int ldc, int cMod,
                  int K,
                  const bf16* __restrict__ wout, int woutMod,
                  float* __restrict__ logits) {
    constexpr int BK = 32;
    constexpr int WM = BM / 2, WN = BN / 2;
    constexpr int TM = WM / 16, TN = WN / 16;
    constexpr int A_W = BM / 64;   // wave-loads per wave for A tile
    constexpr int B_W = BN / 64;

    __shared__ __align__(16) bf16 sA[BM][BK];
    __shared__ __align__(16) bf16 sB[BN][BK];

    const int tid = threadIdx.x;
    const int wid = tid >> 6;
    const int lane = tid & 63;
    const int wm = wid >> 1, wn = wid & 1;
    const int q = lane >> 4, ln = lane & 15;
    const int lr = lane >> 2, lk = lane & 3;   // staging row-in-group / k-chunk

    const int m = blockIdx.z;
    const bf16* Am = A + (size_t)m * aMod;
    const bf16* Wm = W + (size_t)m * wMod;

    const int r0 = blockIdx.y * BM;   // batch-row tile origin
    const int c0 = blockIdx.x * BN;   // out-col tile origin

    // staging pointers (k0 = 0); advance global side by k0 each iter
    const bf16* gA[A_W];
    bf16* lA[A_W];
#pragma unroll
    for (int t = 0; t < A_W; ++t) {
        int grp = wid * A_W + t;
        gA[t] = Am + (size_t)(r0 + grp * 16 + lr) * lda + lk * 8;
        lA[t] = &sA[grp * 16][0];
    }
    const bf16* gB[B_W];
    bf16* lB[B_W];
#pragma unroll
    for (int t = 0; t < B_W; ++t) {
        int grp = wid * B_W + t;
        gB[t] = Wm + (size_t)(c0 + grp * 16 + lr) * K + lk * 8;
        lB[t] = &sB[grp * 16][0];
    }

    f32x4 acc[TM][TN];
#pragma unroll
    for (int i = 0; i < TM; ++i)
#pragma unroll
        for (int j = 0; j < TN; ++j)
            acc[i][j] = (f32x4){0.f, 0.f, 0.f, 0.f};

    for (int k0 = 0; k0 < K; k0 += BK) {
#pragma unroll
        for (int t = 0; t < A_W; ++t) gload16_lds(gA[t] + k0, lA[t]);
#pragma unroll
        for (int t = 0; t < B_W; ++t) gload16_lds(gB[t] + k0, lB[t]);
        __syncthreads();   // compiler drains vmcnt before s_barrier

        bf16x8 aF[TM], bF[TN];
#pragma unroll
        for (int i = 0; i < TM; ++i)
            aF[i] = *(const bf16x8*)&sA[wm * WM + i * 16 + ln][q * 8];
#pragma unroll
        for (int j = 0; j < TN; ++j)
            bF[j] = *(const bf16x8*)&sB[wn * WN + j * 16 + ln][q * 8];
#pragma unroll
        for (int i = 0; i < TM; ++i)
#pragma unroll
            for (int j = 0; j < TN; ++j)
                acc[i][j] = __builtin_amdgcn_mfma_f32_16x16x32_bf16(aF[i], bF[j], acc[i][j], 0, 0, 0);
        __syncthreads();   // protect LDS before next stage
    }

    const float* biasm = bias + (size_t)m * biasMod;

    if (!FUSE) {
        bf16* Cm = C + (size_t)m * cMod;
#pragma unroll
        for (int j = 0; j < TN; ++j) {
            int col = c0 + wn * WN + j * 16 + ln;
            float bv = biasm[col];
#pragma unroll
            for (int i = 0; i < TM; ++i) {
#pragma unroll
                for (int r = 0; r < 4; ++r) {
                    int row = r0 + wm * WM + i * 16 + q * 4 + r;
                    float v = acc[i][j][r] + bv;
                    v = v > 0.f ? v : 0.f;
                    Cm[(size_t)row * ldc + col] = __float2bfloat16(v);
                }
            }
        }
    } else {
        // fused output layer: logits[row][m] += sum_col relu(v) * wout[m][col]
        const bf16* wom = wout + (size_t)m * woutMod;
        float wv[TN], bvv[TN];
#pragma unroll
        for (int j = 0; j < TN; ++j) {
            int col = c0 + wn * WN + j * 16 + ln;
            wv[j] = __bfloat162float(wom[col]);
            bvv[j] = biasm[col];
        }
#pragma unroll
        for (int i = 0; i < TM; ++i) {
#pragma unroll
            for (int r = 0; r < 4; ++r) {
                float p = 0.f;
#pragma unroll
                for (int j = 0; j < TN; ++j) {
                    float v = acc[i][j][r] + bvv[j];
                    v = v > 0.f ? v : 0.f;
                    p += v * wv[j];
                }
                // reduce over the 16 column-lanes of this quad (xor keeps quad bits)
                p += __shfl_xor(p, 1);
                p += __shfl_xor(p, 2);
                p += __shfl_xor(p, 4);
                p += __shfl_xor(p, 8);
                if (ln == 0) {
                    int row = r0 + wm * WM + i * 16 + q * 4 + r;
                    atomicAdd(&logits[(size_t)row * M_ + m], p);
                }
            }
        }
    }
}

// ---------------- host ----------------
extern "C" void kernel_launch(void* const* d_in, const int* in_sizes, int n_in,
                              void* d_out, int out_size, void* d_ws, size_t ws_size,
                              hipStream_t stream) {
    const float* x    = (const float*)d_in[0];
    const float* W0   = (const float*)d_in[1];
    const float* b0   = (const float*)d_in[2];
    const float* W1   = (const float*)d_in[3];
    const float* b1   = (const float*)d_in[4];
    const float* W2   = (const float*)d_in[5];
    const float* b2   = (const float*)d_in[6];
    const float* W3   = (const float*)d_in[7];
    const float* b3   = (const float*)d_in[8];
    const float* W4   = (const float*)d_in[9];
    const float* b4   = (const float*)d_in[10];
    const float* Wout = (const float*)d_in[11];
    const float* bout = (const float*)d_in[12];
    float* out = (float*)d_out;

    // workspace carve-up (all 256B-aligned), ~203 MiB total
    char* ws = (char*)d_ws;
    size_t off = 0;
    auto alloc = [&](size_t bytes) -> void* {
        off = (off + 255) & ~(size_t)255;
        void* p = ws + off;
        off += bytes;
        return p;
    };
    bf16* W0b   = (bf16*)alloc((size_t)4096 * 4096 * 2);
    bf16* W1b   = (bf16*)alloc((size_t)M_ * 64 * 32 * 2);
    bf16* W2b   = (bf16*)alloc((size_t)M_ * 128 * 64 * 2);
    bf16* W3b   = (bf16*)alloc((size_t)M_ * 256 * 128 * 2);
    bf16* W4b   = (bf16*)alloc((size_t)M_ * 512 * 256 * 2);
    bf16* Woutb = (bf16*)alloc((size_t)M_ * 512 * 2);
    bf16* xb    = (bf16*)alloc((size_t)B_ * 4096 * 2);
    bf16* h0    = (bf16*)alloc((size_t)B_ * 4096 * 2);          // [B][128][32]
    bf16* h1    = (bf16*)alloc((size_t)B_ * M_ * 64 * 2);       // [B][128][64]
    bf16* h2    = (bf16*)alloc((size_t)B_ * M_ * 128 * 2);      // [B][128][128]
    bf16* h3    = (bf16*)alloc((size_t)B_ * M_ * 256 * 2);      // [B][128][256]
    float* logits = (float*)alloc((size_t)B_ * M_ * 4);

    // single fused conversion kernel for x + all weights
    CvtArgs ca;
    ca.src[0] = (const float4*)x;    ca.dst[0] = (short4*)xb;
    ca.src[1] = (const float4*)W0;   ca.dst[1] = (short4*)W0b;
    ca.src[2] = (const float4*)W1;   ca.dst[2] = (short4*)W1b;
    ca.src[3] = (const float4*)W2;   ca.dst[3] = (short4*)W2b;
    ca.src[4] = (const float4*)W3;   ca.dst[4] = (short4*)W3b;
    ca.src[5] = (const float4*)W4;   ca.dst[5] = (short4*)W4b;
    ca.src[6] = (const float4*)Wout; ca.dst[6] = (short4*)Woutb;
    cvt_all<<<(10829824 + 255) / 256, 256, 0, stream>>>(ca);

    // L0: h0[1024,4096] = relu(xb @ W0b^T + b0) — 128x64 tiles, 512 blocks
    {
        dim3 g(4096 / 64, B_ / 128, 1);
        gemm_bt_relu<128, 64, false><<<g, 256, 0, stream>>>(
            xb, 4096, 0, W0b, 0, b0, 0, h0, 4096, 0, 4096, nullptr, 0, nullptr);
    }
    // L1: per-module 32->64
    {
        dim3 g(64 / 64, B_ / 64, M_);
        gemm_bt_relu<64, 64, false><<<g, 256, 0, stream>>>(
            h0, 4096, 32, W1b, 64 * 32, b1, 64, h1, M_ * 64, 64, 32, nullptr, 0, nullptr);
    }
    // L2: per-module 64->128
    {
        dim3 g(128 / 64, B_ / 64, M_);
        gemm_bt_relu<64, 64, false><<<g, 256, 0, stream>>>(
            h1, M_ * 64, 64, W2b, 128 * 64, b2, 128, h2, M_ * 128, 128, 64, nullptr, 0, nullptr);
    }
    // L3: per-module 128->256
    {
        dim3 g(256 / 128, B_ / 128, M_);
        gemm_bt_relu<128, 128, false><<<g, 256, 0, stream>>>(
            h2, M_ * 128, 128, W3b, 256 * 128, b3, 256, h3, M_ * 256, 256, 128, nullptr, 0, nullptr);
    }
    // zero logits, then L4 (per-module 256->512) with fused Wout dot
    zero_f32<<<(B_ * M_ + 255) / 256, 256, 0, stream>>>(logits, B_ * M_);
    {
        dim3 g(512 / 128, B_ / 128, M_);
        gemm_bt_relu<128, 128, true><<<g, 256, 0, stream>>>(
            h3, M_ * 256, 256, W4b, 512 * 256, b4, 512, nullptr, 0, 0, 256, Woutb, 512, logits);
    }
    final_sigmoid<<<(B_ * M_ + 255) / 256, 256, 0, stream>>>(logits, bout, out, B_ * M_);
}

// Round 3
// 356.677 us; speedup vs baseline: 1.4156x; 1.1662x over previous
//
#include <hip/hip_runtime.h>
#include <hip/hip_bf16.h>

// MaskMLP: x[1024,4096] -> L0 dense (4096->128*32) -> 4 block-diagonal layers
// (per-module 32->64->128->256->512) -> per-module dot with Wout -> sigmoid.
// R3: fuse L1..L4+out into ONE kernel: block = (module, 64-row strip).
// Activations live in a 64 KiB LDS pool (phase-overlapped regions); weights
// stream via global_load_lds in 32-k chunks. Chunk-XOR swizzle (slot =
// c ^ (row & (C-1))) keeps staging coalesced AND frag ds_read_b128 nearly
// conflict-free. Output logits reduced in-block -> direct sigmoid store
// (no atomics, no intermediate HBM round-trips).

using bf16 = __hip_bfloat16;
typedef short bf16x8 __attribute__((ext_vector_type(8)));   // 8 bf16 = 4 VGPRs
typedef float f32x4 __attribute__((ext_vector_type(4)));

constexpr int B_ = 1024;   // batch
constexpr int M_ = 128;    // modules

// ---------------- async global->LDS, 16B per lane ----------------
// HW: LDS dest = wave-uniform base + lane*16 (m104/m108).
__device__ __forceinline__ void gload16_lds(const bf16* gp, bf16* lp) {
    __builtin_amdgcn_global_load_lds(
        (__attribute__((address_space(1))) void*)const_cast<bf16*>(gp),
        (__attribute__((address_space(3))) void*)lp,
        16, 0, 0);
}

// ---------------- fused fp32 -> bf16 conversion (x, W0, W1..W4) ----------------
struct CvtArgs {
    const float4* src[6];
    short4* dst[6];
};
__global__ void cvt_all(CvtArgs a) {
    // cumulative float4 counts: x, W0, W1, W2, W3, W4
    constexpr int starts[7] = {0, 1048576, 5242880, 5308416, 5570560,
                               6619136, 10813440};
    int i = blockIdx.x * blockDim.x + threadIdx.x;
    if (i >= starts[6]) return;
    int s = 0;
#pragma unroll
    for (int k = 1; k < 6; ++k) s += (i >= starts[k]) ? 1 : 0;
    int off = i - starts[s];
    float4 v = a.src[s][off];
    union { bf16 h[4]; short4 s4; } u;
    u.h[0] = __float2bfloat16(v.x);
    u.h[1] = __float2bfloat16(v.y);
    u.h[2] = __float2bfloat16(v.z);
    u.h[3] = __float2bfloat16(v.w);
    a.dst[s][off] = u.s4;
}

// ---------------- L0 dense GEMM:  C = relu(A @ W^T + bias)  (R2-verified) ----------------
// LDS row-major [rows][32] (64B rows); staging via global_load_lds: wave-load
// covers 16 rows x 32k, lane -> (row=lane/4, kchunk=lane%4).
template<int BM, int BN>
__global__ __launch_bounds__(256)
void gemm_bt_relu(const bf16* __restrict__ A, int lda,
                  const bf16* __restrict__ W,
                  const float* __restrict__ bias,
                  bf16* __restrict__ C, int ldc,
                  int K) {
    constexpr int BK = 32;
    constexpr int WM = BM / 2, WN = BN / 2;
    constexpr int TM = WM / 16, TN = WN / 16;
    constexpr int A_W = BM / 64;
    constexpr int B_W = BN / 64;

    __shared__ __align__(16) bf16 sA[BM][BK];
    __shared__ __align__(16) bf16 sB[BN][BK];

    const int tid = threadIdx.x;
    const int wid = tid >> 6;
    const int lane = tid & 63;
    const int wm = wid >> 1, wn = wid & 1;
    const int q = lane >> 4, ln = lane & 15;
    const int lr = lane >> 2, lk = lane & 3;

    const int r0 = blockIdx.y * BM;
    const int c0 = blockIdx.x * BN;

    const bf16* gA[A_W];
    bf16* lA[A_W];
#pragma unroll
    for (int t = 0; t < A_W; ++t) {
        int grp = wid * A_W + t;
        gA[t] = A + (size_t)(r0 + grp * 16 + lr) * lda + lk * 8;
        lA[t] = &sA[grp * 16][0];
    }
    const bf16* gB[B_W];
    bf16* lB[B_W];
#pragma unroll
    for (int t = 0; t < B_W; ++t) {
        int grp = wid * B_W + t;
        gB[t] = W + (size_t)(c0 + grp * 16 + lr) * K + lk * 8;
        lB[t] = &sB[grp * 16][0];
    }

    f32x4 acc[TM][TN];
#pragma unroll
    for (int i = 0; i < TM; ++i)
#pragma unroll
        for (int j = 0; j < TN; ++j)
            acc[i][j] = (f32x4){0.f, 0.f, 0.f, 0.f};

    for (int k0 = 0; k0 < K; k0 += BK) {
#pragma unroll
        for (int t = 0; t < A_W; ++t) gload16_lds(gA[t] + k0, lA[t]);
#pragma unroll
        for (int t = 0; t < B_W; ++t) gload16_lds(gB[t] + k0, lB[t]);
        __syncthreads();

        bf16x8 aF[TM], bF[TN];
#pragma unroll
        for (int i = 0; i < TM; ++i)
            aF[i] = *(const bf16x8*)&sA[wm * WM + i * 16 + ln][q * 8];
#pragma unroll
        for (int j = 0; j < TN; ++j)
            bF[j] = *(const bf16x8*)&sB[wn * WN + j * 16 + ln][q * 8];
#pragma unroll
        for (int i = 0; i < TM; ++i)
#pragma unroll
            for (int j = 0; j < TN; ++j)
                acc[i][j] = __builtin_amdgcn_mfma_f32_16x16x32_bf16(aF[i], bF[j], acc[i][j], 0, 0, 0);
        __syncthreads();
    }

#pragma unroll
    for (int j = 0; j < TN; ++j) {
        int col = c0 + wn * WN + j * 16 + ln;
        float bv = bias[col];
#pragma unroll
        for (int i = 0; i < TM; ++i) {
#pragma unroll
            for (int r = 0; r < 4; ++r) {
                int row = r0 + wm * WM + i * 16 + q * 4 + r;
                float v = acc[i][j][r] + bv;
                v = v > 0.f ? v : 0.f;
                C[(size_t)row * ldc + col] = __float2bfloat16(v);
            }
        }
    }
}

// ---------------- fully-fused module chain: h0 -> L1..L4 -> wout -> sigmoid ----------------
// grid (16 strips, 128 modules), 256 threads (4 waves). Each block: 64 batch
// rows of one module, all intermediates in LDS.
// LDS pool (bf16 elems, 32768 = 64 KiB):
//   h3 [0,16384)  h2 [16384,24576)  h1 [24576,28672)  h0 [28672,30720)
//   Wbuf: P1 @30720(2K elems)  P2 @28672(4K, over h0)  P3 @24576(8K, over h1)
//         P4 @16384(8K, over h2)   logit scratch: floats @16384 (after P4)
__global__ __launch_bounds__(256)
void modules_fused(const bf16* __restrict__ h0g,
                   const bf16* __restrict__ W1b, const float* __restrict__ b1,
                   const bf16* __restrict__ W2b, const float* __restrict__ b2,
                   const bf16* __restrict__ W3b, const float* __restrict__ b3,
                   const bf16* __restrict__ W4b, const float* __restrict__ b4,
                   const float* __restrict__ Wout, const float* __restrict__ bout,
                   float* __restrict__ out) {
    constexpr int H3O = 0, H2O = 16384, H1O = 24576, H0O = 28672;
    constexpr int W1O = 30720, W2O = 28672, W3O = 24576, W4O = 16384;
    __shared__ __align__(16) bf16 pool[32768];

    const int tid = threadIdx.x, w = tid >> 6, lane = tid & 63;
    const int q = lane >> 4, ln = lane & 15;
    const int lr = lane >> 2, lk = lane & 3;
    const int swz = (lk ^ (lr & 3)) * 8;          // global-side chunk swizzle
    const int m = blockIdx.y;
    const int r0 = blockIdx.x * 64;

    const bf16* W1m = W1b + (size_t)m * 64 * 32;
    const bf16* W2m = W2b + (size_t)m * 128 * 64;
    const bf16* W3m = W3b + (size_t)m * 256 * 128;
    const bf16* W4m = W4b + (size_t)m * 512 * 256;

    // stage `rows` x 32k of G (row stride ldg) rows nr0.., k k0.. into pool+woff
    auto stageW = [&](const bf16* G, int ldg, int rows, int nr0, int k0, int woff) {
        for (int t = 0; t < rows / 64; ++t) {
            int r = t * 64 + w * 16 + lr;
            gload16_lds(G + (size_t)(nr0 + r) * ldg + k0 + swz,
                        pool + woff + t * 2048 + w * 512);
        }
    };
    // A-fragment: 8 bf16 of (row, k-chunk kc) from swizzled h-buffer (C chunks/row)
    auto readA = [&](int hoff, int C, int row, int kc) -> bf16x8 {
        return *(const bf16x8*)&pool[hoff + row * (C * 8) + ((kc ^ (row & (C - 1))) * 8)];
    };
    // B-fragment from Wbuf (always C=4, current 32-k window), rn = local n-row
    auto readB = [&](int woff, int rn) -> bf16x8 {
        return *(const bf16x8*)&pool[woff + rn * 32 + ((q ^ (rn & 3)) * 8)];
    };
    // scalar write into swizzled h-buffer
    auto writeH = [&](int hoff, int C, int row, int col, float v) {
        pool[hoff + row * (C * 8) + (((col >> 3) ^ (row & (C - 1))) * 8) + (col & 7)] =
            __float2bfloat16(v);
    };

    // ---- P1: stage h0 strip (64x32) + W1; h1 = relu(h0 @ W1^T + b1) ----
    gload16_lds(h0g + (size_t)(r0 + w * 16 + lr) * 4096 + m * 32 + swz,
                pool + H0O + w * 512);
    stageW(W1m, 32, 64, 0, 0, W1O);
    __syncthreads();
    {
        f32x4 a1[4];
#pragma unroll
        for (int i = 0; i < 4; ++i) a1[i] = (f32x4){0.f, 0.f, 0.f, 0.f};
        bf16x8 bfr = readB(W1O, w * 16 + ln);
#pragma unroll
        for (int i = 0; i < 4; ++i) {
            bf16x8 af = readA(H0O, 4, i * 16 + ln, q);
            a1[i] = __builtin_amdgcn_mfma_f32_16x16x32_bf16(af, bfr, a1[i], 0, 0, 0);
        }
        int col = w * 16 + ln;
        float bb = b1[m * 64 + col];
#pragma unroll
        for (int i = 0; i < 4; ++i)
#pragma unroll
            for (int r = 0; r < 4; ++r) {
                float v = a1[i][r] + bb;
                v = v > 0.f ? v : 0.f;
                writeH(H1O, 8, i * 16 + q * 4 + r, col, v);
            }
    }
    __syncthreads();

    // ---- P2: h2 = relu(h1 @ W2^T + b2)   K=64 (2 rounds), N=128 ----
    {
        f32x4 a2[4][2];
#pragma unroll
        for (int i = 0; i < 4; ++i)
#pragma unroll
            for (int j = 0; j < 2; ++j) a2[i][j] = (f32x4){0.f, 0.f, 0.f, 0.f};
#pragma unroll
        for (int kr = 0; kr < 2; ++kr) {
            stageW(W2m, 64, 128, 0, kr * 32, W2O);
            __syncthreads();
            bf16x8 bfr[2];
#pragma unroll
            for (int j = 0; j < 2; ++j) bfr[j] = readB(W2O, w * 32 + j * 16 + ln);
#pragma unroll
            for (int i = 0; i < 4; ++i) {
                bf16x8 af = readA(H1O, 8, i * 16 + ln, kr * 4 + q);
#pragma unroll
                for (int j = 0; j < 2; ++j)
                    a2[i][j] = __builtin_amdgcn_mfma_f32_16x16x32_bf16(af, bfr[j], a2[i][j], 0, 0, 0);
            }
            __syncthreads();
        }
#pragma unroll
        for (int j = 0; j < 2; ++j) {
            int col = w * 32 + j * 16 + ln;
            float bb = b2[m * 128 + col];
#pragma unroll
            for (int i = 0; i < 4; ++i)
#pragma unroll
                for (int r = 0; r < 4; ++r) {
                    float v = a2[i][j][r] + bb;
                    v = v > 0.f ? v : 0.f;
                    writeH(H2O, 16, i * 16 + q * 4 + r, col, v);
                }
        }
    }
    __syncthreads();

    // ---- P3: h3 = relu(h2 @ W3^T + b3)   K=128 (4 rounds), N=256 ----
    {
        f32x4 a3[4][4];
#pragma unroll
        for (int i = 0; i < 4; ++i)
#pragma unroll
            for (int j = 0; j < 4; ++j) a3[i][j] = (f32x4){0.f, 0.f, 0.f, 0.f};
#pragma unroll
        for (int kr = 0; kr < 4; ++kr) {
            stageW(W3m, 128, 256, 0, kr * 32, W3O);
            __syncthreads();
            bf16x8 bfr[4];
#pragma unroll
            for (int j = 0; j < 4; ++j) bfr[j] = readB(W3O, w * 64 + j * 16 + ln);
#pragma unroll
            for (int i = 0; i < 4; ++i) {
                bf16x8 af = readA(H2O, 16, i * 16 + ln, kr * 4 + q);
#pragma unroll
                for (int j = 0; j < 4; ++j)
                    a3[i][j] = __builtin_amdgcn_mfma_f32_16x16x32_bf16(af, bfr[j], a3[i][j], 0, 0, 0);
            }
            __syncthreads();
        }
#pragma unroll
        for (int j = 0; j < 4; ++j) {
            int col = w * 64 + j * 16 + ln;
            float bb = b3[m * 256 + col];
#pragma unroll
            for (int i = 0; i < 4; ++i)
#pragma unroll
                for (int r = 0; r < 4; ++r) {
                    float v = a3[i][j][r] + bb;
                    v = v > 0.f ? v : 0.f;
                    writeH(H3O, 32, i * 16 + q * 4 + r, col, v);
                }
        }
    }
    __syncthreads();

    // ---- P4: L4 (K=256, N=512 in 2 n-chunks) + fused Wout dot ----
    float pl[4][4];
#pragma unroll
    for (int i = 0; i < 4; ++i)
#pragma unroll
        for (int r = 0; r < 4; ++r) pl[i][r] = 0.f;

#pragma unroll
    for (int nc = 0; nc < 2; ++nc) {
        f32x4 a4[4][4];
#pragma unroll
        for (int i = 0; i < 4; ++i)
#pragma unroll
            for (int j = 0; j < 4; ++j) a4[i][j] = (f32x4){0.f, 0.f, 0.f, 0.f};
#pragma unroll
        for (int kr = 0; kr < 8; ++kr) {
            stageW(W4m, 256, 256, nc * 256, kr * 32, W4O);
            __syncthreads();
            bf16x8 bfr[4];
#pragma unroll
            for (int j = 0; j < 4; ++j) bfr[j] = readB(W4O, w * 64 + j * 16 + ln);
#pragma unroll
            for (int i = 0; i < 4; ++i) {
                bf16x8 af = readA(H3O, 32, i * 16 + ln, kr * 4 + q);
#pragma unroll
                for (int j = 0; j < 4; ++j)
                    a4[i][j] = __builtin_amdgcn_mfma_f32_16x16x32_bf16(af, bfr[j], a4[i][j], 0, 0, 0);
            }
            __syncthreads();
        }
        // per-chunk epilogue: accumulate relu(v)*wout into per-lane partials
#pragma unroll
        for (int j = 0; j < 4; ++j) {
            int col = nc * 256 + w * 64 + j * 16 + ln;
            float bb = b4[m * 512 + col];
            float wv = Wout[m * 512 + col];
#pragma unroll
            for (int i = 0; i < 4; ++i)
#pragma unroll
                for (int r = 0; r < 4; ++r) {
                    float v = a4[i][j][r] + bb;
                    v = v > 0.f ? v : 0.f;
                    pl[i][r] += v * wv;
                }
        }
    }

    // ---- reduce partials: 16 col-lanes via shuffle, 4 waves via LDS ----
    float* sc = (float*)&pool[W4O];   // 4*64 floats; safe after last barrier
#pragma unroll
    for (int i = 0; i < 4; ++i)
#pragma unroll
        for (int r = 0; r < 4; ++r) {
            float p = pl[i][r];
            p += __shfl_xor(p, 1);
            p += __shfl_xor(p, 2);
            p += __shfl_xor(p, 4);
            p += __shfl_xor(p, 8);
            if (ln == 0) sc[w * 64 + i * 16 + q * 4 + r] = p;
        }
    __syncthreads();
    if (tid < 64) {
        float s = sc[tid] + sc[64 + tid] + sc[128 + tid] + sc[192 + tid];
        float lg = s + bout[m];
        out[(size_t)(r0 + tid) * M_ + m] = 1.f / (1.f + __expf(-lg));
    }
}

// ---------------- host ----------------
extern "C" void kernel_launch(void* const* d_in, const int* in_sizes, int n_in,
                              void* d_out, int out_size, void* d_ws, size_t ws_size,
                              hipStream_t stream) {
    const float* x    = (const float*)d_in[0];
    const float* W0   = (const float*)d_in[1];
    const float* b0   = (const float*)d_in[2];
    const float* W1   = (const float*)d_in[3];
    const float* b1   = (const float*)d_in[4];
    const float* W2   = (const float*)d_in[5];
    const float* b2   = (const float*)d_in[6];
    const float* W3   = (const float*)d_in[7];
    const float* b3   = (const float*)d_in[8];
    const float* W4   = (const float*)d_in[9];
    const float* b4   = (const float*)d_in[10];
    const float* Wout = (const float*)d_in[11];
    const float* bout = (const float*)d_in[12];
    float* out = (float*)d_out;

    char* ws = (char*)d_ws;
    size_t off = 0;
    auto alloc = [&](size_t bytes) -> void* {
        off = (off + 255) & ~(size_t)255;
        void* p = ws + off;
        off += bytes;
        return p;
    };
    bf16* W0b = (bf16*)alloc((size_t)4096 * 4096 * 2);
    bf16* W1b = (bf16*)alloc((size_t)M_ * 64 * 32 * 2);
    bf16* W2b = (bf16*)alloc((size_t)M_ * 128 * 64 * 2);
    bf16* W3b = (bf16*)alloc((size_t)M_ * 256 * 128 * 2);
    bf16* W4b = (bf16*)alloc((size_t)M_ * 512 * 256 * 2);
    bf16* xb  = (bf16*)alloc((size_t)B_ * 4096 * 2);
    bf16* h0  = (bf16*)alloc((size_t)B_ * 4096 * 2);   // [B][128][32]

    CvtArgs ca;
    ca.src[0] = (const float4*)x;  ca.dst[0] = (short4*)xb;
    ca.src[1] = (const float4*)W0; ca.dst[1] = (short4*)W0b;
    ca.src[2] = (const float4*)W1; ca.dst[2] = (short4*)W1b;
    ca.src[3] = (const float4*)W2; ca.dst[3] = (short4*)W2b;
    ca.src[4] = (const float4*)W3; ca.dst[4] = (short4*)W3b;
    ca.src[5] = (const float4*)W4; ca.dst[5] = (short4*)W4b;
    cvt_all<<<(10813440 + 255) / 256, 256, 0, stream>>>(ca);

    // L0: h0[1024,4096] = relu(xb @ W0b^T + b0) — 128x64 tiles, 512 blocks
    {
        dim3 g(4096 / 64, B_ / 128, 1);
        gemm_bt_relu<128, 64><<<g, 256, 0, stream>>>(xb, 4096, W0b, b0, h0, 4096, 4096);
    }
    // fused L1..L4 + output layer + sigmoid
    {
        dim3 g(B_ / 64, M_, 1);
        modules_fused<<<g, 256, 0, stream>>>(h0, W1b, b1, W2b, b2, W3b, b3,
                                             W4b, b4, Wout, bout, out);
    }
}

// Round 4
// 323.766 us; speedup vs baseline: 1.5595x; 1.1016x over previous
//
#include <hip/hip_runtime.h>
#include <hip/hip_bf16.h>

// MaskMLP R4: software-pipelined weight streaming with hand vmcnt bookkeeping.
// - modules_fused: 23 rounds -> raw s_barrier + s_waitcnt vmcnt(N) pipeline
//   (P2 prestaged, P3 dist-1 dbuf, P4 dist-2 triple-buffer), padded h-strides
//   (+8 elems -> 4-bank/row rotation: frag reads conflict-free, epilogue
//   writes 2-way=free), epilogue scalars preloaded to keep vmcnt counts exact.
// - gemm_l0: BK=64 double-buffered dist-2 pipeline, 49KB LDS -> 3 blocks/CU.

using bf16 = __hip_bfloat16;
typedef short bf16x8 __attribute__((ext_vector_type(8)));   // 8 bf16 = 4 VGPRs
typedef float f32x4 __attribute__((ext_vector_type(4)));

constexpr int B_ = 1024;   // batch
constexpr int M_ = 128;    // modules

// raw waits/barrier: memory clobber stops the compiler moving LDS/global ops
// across them; s_waitcnt mnemonic leaves unmentioned counters at no-wait.
#define WAITV(N) asm volatile("s_waitcnt vmcnt(" #N ")" ::: "memory")
#define WAITL()  asm volatile("s_waitcnt lgkmcnt(0)" ::: "memory")
#define BAR()    asm volatile("s_barrier" ::: "memory")

// async global->LDS, 16B/lane; LDS dest = wave-uniform base + lane*16.
__device__ __forceinline__ void gload16_lds(const bf16* gp, bf16* lp) {
    __builtin_amdgcn_global_load_lds(
        (__attribute__((address_space(1))) void*)const_cast<bf16*>(gp),
        (__attribute__((address_space(3))) void*)lp,
        16, 0, 0);
}

// ---------------- fused fp32 -> bf16 conversion (x, W0..W4) ----------------
struct CvtArgs {
    const float4* src[6];
    short4* dst[6];
};
__global__ void cvt_all(CvtArgs a) {
    constexpr int starts[7] = {0, 1048576, 5242880, 5308416, 5570560,
                               6619136, 10813440};
    int i = blockIdx.x * blockDim.x + threadIdx.x;
    if (i >= starts[6]) return;
    int s = 0;
#pragma unroll
    for (int k = 1; k < 6; ++k) s += (i >= starts[k]) ? 1 : 0;
    int off = i - starts[s];
    float4 v = a.src[s][off];
    union { bf16 h[4]; short4 s4; } u;
    u.h[0] = __float2bfloat16(v.x);
    u.h[1] = __float2bfloat16(v.y);
    u.h[2] = __float2bfloat16(v.z);
    u.h[3] = __float2bfloat16(v.w);
    a.dst[s][off] = u.s4;
}

// ---------------- L0: h0 = relu(x @ W0^T + b0), K=4096 ----------------
// 128x64 tile, BK=64 (two 32-k halves per stage), 2 LDS sets, prefetch dist 2.
__global__ __launch_bounds__(256, 2)
void gemm_l0(const bf16* __restrict__ A, const bf16* __restrict__ W,
             const float* __restrict__ bias, bf16* __restrict__ C) {
    constexpr int LDA = 4096;
    __shared__ __align__(16) bf16 sA[2][2][128 * 32];   // [set][half][row*32]
    __shared__ __align__(16) bf16 sB[2][2][64 * 32];

    const int tid = threadIdx.x, w = tid >> 6, lane = tid & 63;
    const int q = lane >> 4, ln = lane & 15;
    const int lr = lane >> 2, lk = lane & 3;
    const int swz = (lk ^ (lr & 3)) * 8;
    const int wm = w >> 1, wn = w & 1;
    const int r0 = blockIdx.y * 128, c0 = blockIdx.x * 64;

    auto stage = [&](int s, int set) {   // 6 gloads/wave
        const int k0 = s * 64;
#pragma unroll
        for (int h = 0; h < 2; ++h) {
#pragma unroll
            for (int t = 0; t < 2; ++t) {
                int grp = w * 2 + t;
                gload16_lds(A + (size_t)(r0 + grp * 16 + lr) * LDA + k0 + h * 32 + swz,
                            &sA[set][h][grp * 512]);
            }
            gload16_lds(W + (size_t)(c0 + w * 16 + lr) * LDA + k0 + h * 32 + swz,
                        &sB[set][h][w * 512]);
        }
    };

    f32x4 acc[4][2];
#pragma unroll
    for (int i = 0; i < 4; ++i)
#pragma unroll
        for (int j = 0; j < 2; ++j) acc[i][j] = (f32x4){0.f, 0.f, 0.f, 0.f};

    stage(0, 0);
    stage(1, 1);
    for (int r = 0; r < 64; ++r) {
        if (r < 63) WAITV(6); else WAITV(0);   // current stage arrived
        BAR();
        const int set = r & 1;
        bf16x8 aF[2][4], bF[2][2];
#pragma unroll
        for (int h = 0; h < 2; ++h) {
#pragma unroll
            for (int i = 0; i < 4; ++i) {
                int row = wm * 64 + i * 16 + ln;
                aF[h][i] = *(const bf16x8*)&sA[set][h][row * 32 + ((q ^ (row & 3)) * 8)];
            }
#pragma unroll
            for (int j = 0; j < 2; ++j) {
                int rn = wn * 32 + j * 16 + ln;
                bF[h][j] = *(const bf16x8*)&sB[set][h][rn * 32 + ((q ^ (rn & 3)) * 8)];
            }
        }
        WAITL();
        BAR();                                  // release this set
        if (r + 2 < 64) stage(r + 2, set);      // refill just-freed set
#pragma unroll
        for (int h = 0; h < 2; ++h)
#pragma unroll
            for (int i = 0; i < 4; ++i)
#pragma unroll
                for (int j = 0; j < 2; ++j)
                    acc[i][j] = __builtin_amdgcn_mfma_f32_16x16x32_bf16(
                        aF[h][i], bF[h][j], acc[i][j], 0, 0, 0);
    }

#pragma unroll
    for (int j = 0; j < 2; ++j) {
        int col = c0 + wn * 32 + j * 16 + ln;
        float bv = bias[col];
#pragma unroll
        for (int i = 0; i < 4; ++i)
#pragma unroll
            for (int rr = 0; rr < 4; ++rr) {
                int row = r0 + wm * 64 + i * 16 + q * 4 + rr;
                float v = acc[i][j][rr] + bv;
                v = v > 0.f ? v : 0.f;
                C[(size_t)row * 4096 + col] = __float2bfloat16(v);
            }
    }
}

// ---------------- fused L1..L4 + Wout + sigmoid ----------------
// grid (16 strips, 128 modules), 4 waves. LDS pool (bf16 elems):
//   h3 @0     stride 264, 64 rows -> 16896   (P3 W bufs [0,8192),[8192,16384);
//                                             W1 @8192 during P1)
//   h2 @16896 stride 136 -> 8704             (P4 bufs b0@16896 b1@20992)
//   h1 @25600 stride 72  -> 4608             (P4 buf  b2@25600)
//   h0 @30208 64x32 xor  -> 2048             (logit scratch floats at end)
__global__ __launch_bounds__(256, 2)
void modules_fused(const bf16* __restrict__ h0g,
                   const bf16* __restrict__ W1b, const float* __restrict__ b1,
                   const bf16* __restrict__ W2b, const float* __restrict__ b2,
                   const bf16* __restrict__ W3b, const float* __restrict__ b3,
                   const bf16* __restrict__ W4b, const float* __restrict__ b4,
                   const float* __restrict__ Wout, const float* __restrict__ bout,
                   float* __restrict__ out) {
    constexpr int H3O = 0, H2O = 16896, H1O = 25600, H0O = 30208;
    constexpr int P4B0 = 16896, P4B1 = 20992, P4B2 = 25600;
    __shared__ __align__(16) bf16 pool[32768];

    const int tid = threadIdx.x, w = tid >> 6, lane = tid & 63;
    const int q = lane >> 4, ln = lane & 15;
    const int lr = lane >> 2, lk = lane & 3;
    const int swz = (lk ^ (lr & 3)) * 8;
    const int m = blockIdx.y;
    const int r0 = blockIdx.x * 64;

    const bf16* W1m = W1b + (size_t)m * 64 * 32;
    const bf16* W2m = W2b + (size_t)m * 128 * 64;
    const bf16* W3m = W3b + (size_t)m * 256 * 128;
    const bf16* W4m = W4b + (size_t)m * 512 * 256;

    auto stage = [&](const bf16* G, int ldg, int rows, int nr0, int k0, int woff) {
#pragma unroll
        for (int t = 0; t < rows / 64; ++t) {
            int r = t * 64 + w * 16 + lr;
            gload16_lds(G + (size_t)(nr0 + r) * ldg + k0 + swz,
                        pool + woff + t * 2048 + w * 512);
        }
    };
    auto rdA = [&](int hoff, int stride, int row, int kc) -> bf16x8 {
        return *(const bf16x8*)&pool[hoff + row * stride + kc * 8];
    };
    auto rdA0 = [&](int row) -> bf16x8 {   // h0, xor layout, kc = q
        return *(const bf16x8*)&pool[H0O + row * 32 + ((q ^ (row & 3)) * 8)];
    };
    auto rdB = [&](int woff, int rn) -> bf16x8 {
        return *(const bf16x8*)&pool[woff + rn * 32 + ((q ^ (rn & 3)) * 8)];
    };
    auto wrH = [&](int hoff, int stride, int row, int col, float v) {
        pool[hoff + row * stride + col] = __float2bfloat16(v);
    };

    // ---- preload all epilogue scalars, then drain vmcnt so counts are exact
    float b1v = b1[m * 64 + w * 16 + ln];
    float b2v[2], b3v[4], b4v[4][2], wov[4][2];
#pragma unroll
    for (int j = 0; j < 2; ++j) b2v[j] = b2[m * 128 + w * 32 + j * 16 + ln];
#pragma unroll
    for (int j = 0; j < 4; ++j) b3v[j] = b3[m * 256 + w * 64 + j * 16 + ln];
#pragma unroll
    for (int nc = 0; nc < 4; ++nc)
#pragma unroll
        for (int j = 0; j < 2; ++j) {
            int col = nc * 128 + w * 32 + j * 16 + ln;
            b4v[nc][j] = b4[(size_t)m * 512 + col];
            wov[nc][j] = Wout[(size_t)m * 512 + col];
        }
    float boutv = bout[m];
    WAITV(0);

    // ---- issue: h0 strip (1), W1 (1), P2 s0 (2), P2 s1 (2) -> out=6
    gload16_lds(h0g + (size_t)(r0 + w * 16 + lr) * 4096 + m * 32 + swz,
                pool + H0O + w * 512);
    stage(W1m, 32, 64, 0, 0, 8192);
    stage(W2m, 64, 128, 0, 0, 0);
    stage(W2m, 64, 128, 0, 32, 4096);

    // ================= P1: h1 = relu(h0 @ W1^T + b1) =================
    WAITV(4);   // h0 + W1 arrived; P2 stages remain in flight
    BAR();
    {
        bf16x8 aF[4], bF;
#pragma unroll
        for (int i = 0; i < 4; ++i) aF[i] = rdA0(i * 16 + ln);
        bF = rdB(8192, w * 16 + ln);
        WAITL();
        BAR();
        f32x4 a1[4];
#pragma unroll
        for (int i = 0; i < 4; ++i) {
            a1[i] = (f32x4){0.f, 0.f, 0.f, 0.f};
            a1[i] = __builtin_amdgcn_mfma_f32_16x16x32_bf16(aF[i], bF, a1[i], 0, 0, 0);
        }
        int col = w * 16 + ln;
#pragma unroll
        for (int i = 0; i < 4; ++i)
#pragma unroll
            for (int rr = 0; rr < 4; ++rr) {
                float v = a1[i][rr] + b1v;
                v = v > 0.f ? v : 0.f;
                wrH(H1O, 72, i * 16 + q * 4 + rr, col, v);
            }
        WAITL();
        BAR();   // h1 visible
    }

    // ================= P2: h2 = relu(h1 @ W2^T + b2), 2 rounds =================
    {
        f32x4 a2[4][2];
#pragma unroll
        for (int i = 0; i < 4; ++i)
#pragma unroll
            for (int j = 0; j < 2; ++j) a2[i][j] = (f32x4){0.f, 0.f, 0.f, 0.f};
#pragma unroll
        for (int kr = 0; kr < 2; ++kr) {
            if (kr == 0) WAITV(2); else WAITV(0);
            BAR();
            bf16x8 aF[4], bF[2];
#pragma unroll
            for (int i = 0; i < 4; ++i) aF[i] = rdA(H1O, 72, i * 16 + ln, kr * 4 + q);
#pragma unroll
            for (int j = 0; j < 2; ++j) bF[j] = rdB(kr * 4096, w * 32 + j * 16 + ln);
            WAITL();
            BAR();
            if (kr == 1) {               // P3 s0,s1 (4+4) over consumed P2 bufs
                stage(W3m, 128, 256, 0, 0, 0);
                stage(W3m, 128, 256, 0, 32, 8192);
            }
#pragma unroll
            for (int i = 0; i < 4; ++i)
#pragma unroll
                for (int j = 0; j < 2; ++j)
                    a2[i][j] = __builtin_amdgcn_mfma_f32_16x16x32_bf16(aF[i], bF[j], a2[i][j], 0, 0, 0);
        }
#pragma unroll
        for (int j = 0; j < 2; ++j) {
            int col = w * 32 + j * 16 + ln;
#pragma unroll
            for (int i = 0; i < 4; ++i)
#pragma unroll
                for (int rr = 0; rr < 4; ++rr) {
                    float v = a2[i][j][rr] + b2v[j];
                    v = v > 0.f ? v : 0.f;
                    wrH(H2O, 136, i * 16 + q * 4 + rr, col, v);
                }
        }
        WAITL();
        BAR();   // h2 visible
    }

    // ================= P3: h3 = relu(h2 @ W3^T + b3), 4 rounds, dist-1 =================
    {
        f32x4 a3[4][4];
#pragma unroll
        for (int i = 0; i < 4; ++i)
#pragma unroll
            for (int j = 0; j < 4; ++j) a3[i][j] = (f32x4){0.f, 0.f, 0.f, 0.f};
#pragma unroll
        for (int kr = 0; kr < 4; ++kr) {
            if (kr < 3) WAITV(4); else WAITV(0);
            BAR();
            bf16x8 aF[4], bF[4];
#pragma unroll
            for (int i = 0; i < 4; ++i) aF[i] = rdA(H2O, 136, i * 16 + ln, kr * 4 + q);
#pragma unroll
            for (int j = 0; j < 4; ++j) bF[j] = rdB((kr & 1) * 8192, w * 64 + j * 16 + ln);
            WAITL();
            BAR();
            if (kr == 0)      stage(W3m, 128, 256, 0, 64, 0);       // s2
            else if (kr == 1) stage(W3m, 128, 256, 0, 96, 8192);    // s3
            else if (kr == 3) {                                     // P4 s0,s1
                stage(W4m, 256, 128, 0, 0, P4B0);
                stage(W4m, 256, 128, 0, 32, P4B1);
            }
#pragma unroll
            for (int i = 0; i < 4; ++i)
#pragma unroll
                for (int j = 0; j < 4; ++j)
                    a3[i][j] = __builtin_amdgcn_mfma_f32_16x16x32_bf16(aF[i], bF[j], a3[i][j], 0, 0, 0);
        }
#pragma unroll
        for (int j = 0; j < 4; ++j) {
            int col = w * 64 + j * 16 + ln;
#pragma unroll
            for (int i = 0; i < 4; ++i)
#pragma unroll
                for (int rr = 0; rr < 4; ++rr) {
                    float v = a3[i][j][rr] + b3v[j];
                    v = v > 0.f ? v : 0.f;
                    wrH(H3O, 264, i * 16 + q * 4 + rr, col, v);
                }
        }
        WAITL();
        BAR();   // h3 visible
    }

    // ========== P4: L4 (512 cols in 4 nc-chunks of 128) + Wout dot, dist-2 ==========
    float pl[4][4];
#pragma unroll
    for (int i = 0; i < 4; ++i)
#pragma unroll
        for (int rr = 0; rr < 4; ++rr) pl[i][rr] = 0.f;

#pragma unroll
    for (int nc = 0; nc < 4; ++nc) {
        f32x4 a4[4][2];
#pragma unroll
        for (int i = 0; i < 4; ++i)
#pragma unroll
            for (int j = 0; j < 2; ++j) a4[i][j] = (f32x4){0.f, 0.f, 0.f, 0.f};
#pragma unroll
        for (int kr = 0; kr < 8; ++kr) {
            const int r = nc * 8 + kr;
            if (r + 2 < 32) {   // prefetch into buffer freed after round r-1
                const int r2 = r + 2;
                const int wb2 = (r2 % 3 == 0) ? P4B0 : (r2 % 3 == 1) ? P4B1 : P4B2;
                stage(W4m, 256, 128, (r2 >> 3) * 128, (r2 & 7) * 32, wb2);
            }
            if (r < 30) WAITV(4); else if (r == 30) WAITV(2); else WAITV(0);
            BAR();
            const int wb = (r % 3 == 0) ? P4B0 : (r % 3 == 1) ? P4B1 : P4B2;
            bf16x8 aF[4], bF[2];
#pragma unroll
            for (int i = 0; i < 4; ++i) aF[i] = rdA(H3O, 264, i * 16 + ln, kr * 4 + q);
#pragma unroll
            for (int j = 0; j < 2; ++j) bF[j] = rdB(wb, w * 32 + j * 16 + ln);
            WAITL();
            BAR();
#pragma unroll
            for (int i = 0; i < 4; ++i)
#pragma unroll
                for (int j = 0; j < 2; ++j)
                    a4[i][j] = __builtin_amdgcn_mfma_f32_16x16x32_bf16(aF[i], bF[j], a4[i][j], 0, 0, 0);
        }
#pragma unroll
        for (int j = 0; j < 2; ++j) {
            float bb = b4v[nc][j], wv = wov[nc][j];
#pragma unroll
            for (int i = 0; i < 4; ++i)
#pragma unroll
                for (int rr = 0; rr < 4; ++rr) {
                    float v = a4[i][j][rr] + bb;
                    v = v > 0.f ? v : 0.f;
                    pl[i][rr] += v * wv;
                }
        }
    }

    // ---- reduce: 16 col-lanes via shuffle, 4 waves via LDS, sigmoid store ----
    float* sc = (float*)&pool[H0O];
#pragma unroll
    for (int i = 0; i < 4; ++i)
#pragma unroll
        for (int rr = 0; rr < 4; ++rr) {
            float p = pl[i][rr];
            p += __shfl_xor(p, 1);
            p += __shfl_xor(p, 2);
            p += __shfl_xor(p, 4);
            p += __shfl_xor(p, 8);
            if (ln == 0) sc[w * 64 + i * 16 + q * 4 + rr] = p;
        }
    __syncthreads();   // vmcnt already 0 here; safe
    if (tid < 64) {
        float s = sc[tid] + sc[64 + tid] + sc[128 + tid] + sc[192 + tid];
        float lg = s + boutv;
        out[(size_t)(r0 + tid) * M_ + m] = 1.f / (1.f + __expf(-lg));
    }
}

// ---------------- host ----------------
extern "C" void kernel_launch(void* const* d_in, const int* in_sizes, int n_in,
                              void* d_out, int out_size, void* d_ws, size_t ws_size,
                              hipStream_t stream) {
    const float* x    = (const float*)d_in[0];
    const float* W0   = (const float*)d_in[1];
    const float* b0   = (const float*)d_in[2];
    const float* W1   = (const float*)d_in[3];
    const float* b1   = (const float*)d_in[4];
    const float* W2   = (const float*)d_in[5];
    const float* b2   = (const float*)d_in[6];
    const float* W3   = (const float*)d_in[7];
    const float* b3   = (const float*)d_in[8];
    const float* W4   = (const float*)d_in[9];
    const float* b4   = (const float*)d_in[10];
    const float* Wout = (const float*)d_in[11];
    const float* bout = (const float*)d_in[12];
    float* out = (float*)d_out;

    char* ws = (char*)d_ws;
    size_t off = 0;
    auto alloc = [&](size_t bytes) -> void* {
        off = (off + 255) & ~(size_t)255;
        void* p = ws + off;
        off += bytes;
        return p;
    };
    bf16* W0b = (bf16*)alloc((size_t)4096 * 4096 * 2);
    bf16* W1b = (bf16*)alloc((size_t)M_ * 64 * 32 * 2);
    bf16* W2b = (bf16*)alloc((size_t)M_ * 128 * 64 * 2);
    bf16* W3b = (bf16*)alloc((size_t)M_ * 256 * 128 * 2);
    bf16* W4b = (bf16*)alloc((size_t)M_ * 512 * 256 * 2);
    bf16* xb  = (bf16*)alloc((size_t)B_ * 4096 * 2);
    bf16* h0  = (bf16*)alloc((size_t)B_ * 4096 * 2);   // [B][128][32]

    CvtArgs ca;
    ca.src[0] = (const float4*)x;  ca.dst[0] = (short4*)xb;
    ca.src[1] = (const float4*)W0; ca.dst[1] = (short4*)W0b;
    ca.src[2] = (const float4*)W1; ca.dst[2] = (short4*)W1b;
    ca.src[3] = (const float4*)W2; ca.dst[3] = (short4*)W2b;
    ca.src[4] = (const float4*)W3; ca.dst[4] = (short4*)W3b;
    ca.src[5] = (const float4*)W4; ca.dst[5] = (short4*)W4b;
    cvt_all<<<(10813440 + 255) / 256, 256, 0, stream>>>(ca);

    {
        dim3 g(4096 / 64, B_ / 128, 1);
        gemm_l0<<<g, 256, 0, stream>>>(xb, W0b, b0, h0);
    }
    {
        dim3 g(B_ / 64, M_, 1);
        modules_fused<<<g, 256, 0, stream>>>(h0, W1b, b1, W2b, b2, W3b, b3,
                                             W4b, b4, Wout, bout, out);
    }
}